// Round 3
// baseline (903.038 us; speedup 1.0000x reference)
//
#include <hip/hip_runtime.h>

#define HID 128

typedef __attribute__((ext_vector_type(8))) short short8;
typedef __attribute__((ext_vector_type(4))) float f32x4;

__device__ __forceinline__ float bf2f(unsigned short u) {
  union { unsigned int u; float f; } c; c.u = ((unsigned int)u) << 16; return c.f;
}
__device__ __forceinline__ unsigned short f2bf(float f) {
  union { float f; unsigned int u; } c; c.f = f;
  unsigned int u = c.u;
  return (unsigned short)((u + 0x7FFFu + ((u >> 16) & 1u)) >> 16);  // RNE
}
__device__ __forceinline__ float loads(const void* p, size_t i, bool f32) {
  return f32 ? ((const float*)p)[i] : bf2f(((const unsigned short*)p)[i]);
}
// Load an MFMA A-fragment (8 contiguous k-elements at row*HID+k) as bf16x8.
__device__ __forceinline__ short8 load_a8(const void* base, size_t row, int k, bool f32) {
  if (!f32) return *(const short8*)((const unsigned short*)base + row * HID + k);
  const float* fp = (const float*)base + row * HID + k;
  f32x4 f0 = *(const f32x4*)fp;
  f32x4 f1 = *(const f32x4*)(fp + 4);
  short8 t;
  t[0] = (short)f2bf(f0[0]); t[1] = (short)f2bf(f0[1]);
  t[2] = (short)f2bf(f0[2]); t[3] = (short)f2bf(f0[3]);
  t[4] = (short)f2bf(f1[0]); t[5] = (short)f2bf(f1[1]);
  t[6] = (short)f2bf(f1[2]); t[7] = (short)f2bf(f1[3]);
  return t;
}

// ---------------------------------------------------------------------------
// Runtime dtype detection (worked in round 2: bf16 world detected).
// flags[0]=1 -> float arrays are fp32; flags[1]=1 -> edge_index is int64.
// ---------------------------------------------------------------------------
__global__ void detect_kernel(const void* __restrict__ x,
                              const int* __restrict__ eidx,
                              int* __restrict__ flags) {
  __shared__ int bad, oddnz;
  if (threadIdx.x == 0) { bad = 0; oddnz = 0; }
  __syncthreads();
  const unsigned short* xu = (const unsigned short*)x;
  int mybad = 0;
  for (int i = threadIdx.x; i < 4096; i += 256) {
    int ef = (xu[i] >> 7) & 0xFF;
    if (!(ef == 0 || (ef >= 90 && ef <= 140))) mybad++;
  }
  if (mybad) atomicAdd(&bad, mybad);
  if (threadIdx.x < 128) {
    if (eidx[2 * threadIdx.x + 1] != 0) atomicAdd(&oddnz, 1);
  }
  __syncthreads();
  if (threadIdx.x == 0) {
    flags[0] = (bad > 409) ? 1 : 0;
    flags[1] = (oddnz == 0) ? 1 : 0;
  }
}

__device__ __forceinline__ int get_dst(const int* eidx, bool i64, int E, int e) {
  return i64 ? eidx[2 * (E + e)] : eidx[E + e];
}
__device__ __forceinline__ int get_src(const int* eidx, bool i64, int E, int e) {
  return i64 ? eidx[2 * e] : eidx[e];
}

// Zero d_out (element width per dtype flag). Used only in tiny-ws mode.
__global__ void zero_out_kernel(unsigned int* __restrict__ out,
                                const int* __restrict__ flags, long long nelem) {
  bool f32 = flags[0] != 0;
  size_t words = (size_t)nelem * (f32 ? 2 : 1) / 2;
  for (size_t w = blockIdx.x * 256ull + threadIdx.x; w < words; w += (size_t)gridDim.x * 256ull)
    out[w] = 0u;
}

// ---------------------------------------------------------------------------
// Repack W[K x 128] into MFMA B-fragment order (bf16):
// pack[((ks*8+ct)*64+lane)*8+j] = W[(ks*32+(lane>>4)*8+j)*128 + ct*16+(lane&15)]
// ---------------------------------------------------------------------------
__global__ void repack_all(const void* __restrict__ W1, const void* __restrict__ W2,
                           const void* __restrict__ U1, const void* __restrict__ U2,
                           unsigned short* __restrict__ P1, unsigned short* __restrict__ P2,
                           unsigned short* __restrict__ PU1, unsigned short* __restrict__ PU2,
                           const int* __restrict__ flags) {
  const bool f32 = flags[0] != 0;
  int idx = blockIdx.x * 256 + threadIdx.x;
  const int s1 = 384 * 128, s2 = s1 + 128 * 128, s3 = s2 + 256 * 128, s4 = s3 + 128 * 128;
  if (idx >= s4) return;
  const void* W; unsigned short* P; int off;
  if (idx < s1)      { W = W1; P = P1;  off = idx; }
  else if (idx < s2) { W = W2; P = P2;  off = idx - s1; }
  else if (idx < s3) { W = U1; P = PU1; off = idx - s2; }
  else               { W = U2; P = PU2; off = idx - s3; }
  int j = off & 7, lane = (off >> 3) & 63, ct = (off >> 9) & 7, ks = off >> 12;
  int k = ks * 32 + ((lane >> 4) << 3) + j;
  int n = ct * 16 + (lane & 15);
  P[off] = f2bf(loads(W, (size_t)k * 128 + n, f32));
}

// ---------------------------------------------------------------------------
// Counting sort of edges by dst: histogram -> scan -> scatter.
// ---------------------------------------------------------------------------
__global__ void hist_kernel(const int* __restrict__ eidx, int* __restrict__ counts,
                            const int* __restrict__ flags, int E, int N) {
  const bool i64 = flags[1] != 0;
  int e = blockIdx.x * 256 + threadIdx.x;
  if (e < E) {
    int d = get_dst(eidx, i64, E, e);
    d = min(max(d, 0), N - 1);
    atomicAdd(&counts[d], 1);
  }
}

__global__ __launch_bounds__(1024) void scan_kernel(const int* __restrict__ counts,
                                                    int* __restrict__ offs, int N) {
  __shared__ int wsum[16];
  __shared__ int wpre[16];
  __shared__ int carry_s;
  const int tid = threadIdx.x, lane = tid & 63, wid = tid >> 6;
  if (tid == 0) carry_s = 0;
  __syncthreads();
  for (int base = 0; base < N; base += 1024) {
    int i = base + tid;
    int v = (i < N) ? counts[i] : 0;
    int s = v;
#pragma unroll
    for (int off = 1; off < 64; off <<= 1) {
      int t = __shfl_up(s, off, 64);
      if (lane >= off) s += t;
    }
    if (lane == 63) wsum[wid] = s;
    __syncthreads();
    if (tid == 0) {
      int run = carry_s;
#pragma unroll
      for (int w = 0; w < 16; w++) { int t = wsum[w]; wpre[w] = run; run += t; }
      carry_s = run;
    }
    __syncthreads();
    if (i < N) offs[i] = wpre[wid] + s - v;  // exclusive prefix
    __syncthreads();
  }
  if (tid == 0) offs[N] = carry_s;
}

__global__ void scatter_kernel(const int* __restrict__ eidx, int* __restrict__ cur,
                               int* __restrict__ ssrc, int* __restrict__ sdst,
                               int* __restrict__ perm,
                               const int* __restrict__ flags, int E, int N) {
  const bool i64 = flags[1] != 0;
  int e = blockIdx.x * 256 + threadIdx.x;
  if (e < E) {
    int d = get_dst(eidx, i64, E, e);
    int s = get_src(eidx, i64, E, e);
    d = min(max(d, 0), N - 1);
    s = min(max(s, 0), N - 1);
    int pos = atomicAdd(&cur[d], 1);
    ssrc[pos] = s;
    sdst[pos] = d;
    perm[pos] = e;
  }
}

// ---------------------------------------------------------------------------
// Sorted edge kernel: 64 sorted edges/block; MLP msg; in-tile segmented
// reduction over dst runs; ~6 atomics/col/tile instead of 64.
// LDS: hs (bf16 h-tile, 17.4 KB) unioned with ms (fp32 messages, 33.8 KB).
// ---------------------------------------------------------------------------
__global__ __launch_bounds__(256) void edge_kernel_sorted(
    const void* __restrict__ x, const void* __restrict__ eattr,
    const int* __restrict__ ssrc, const int* __restrict__ sdst,
    const int* __restrict__ perm,
    const unsigned short* __restrict__ P1, const void* __restrict__ b1,
    const unsigned short* __restrict__ P2, const void* __restrict__ b2,
    float* __restrict__ aggf, const int* __restrict__ flags, int E, int N) {
  __shared__ __align__(16) char smem[64 * 132 * 4];  // 33792 B union
  __shared__ int sdst_s[64];
  unsigned short (*hs)[136] = (unsigned short (*)[136])smem;  // first 17408 B
  float (*ms)[132] = (float (*)[132])smem;
  const bool f32 = flags[0] != 0;
  const int tid  = threadIdx.x;
  const int lane = tid & 63;
  const int wid  = tid >> 6;
  const int l15  = lane & 15;
  const int quad = lane >> 4;
  const int base = blockIdx.x * 64;

  if (tid < 64) sdst_s[tid] = sdst[min(base + tid, E - 1)];

  int me = base + wid * 16 + l15;
  if (me >= E) me = E - 1;
  const int src = ssrc[me];
  const int dsm = sdst[me];
  const int pe  = perm[me];

  f32x4 zero = {0.f, 0.f, 0.f, 0.f};
  f32x4 acc[8];
#pragma unroll
  for (int ct = 0; ct < 8; ct++) acc[ct] = zero;

  // GEMM1: [64 x 384] @ [384 x 128]; dst rows are near-uniform per tile (L1 hits)
#pragma unroll
  for (int ks = 0; ks < 12; ks++) {
    const int k0 = ks * 32;
    short8 a;
    if (k0 < 128)      a = load_a8(x,     (size_t)src, k0 + quad * 8, f32);
    else if (k0 < 256) a = load_a8(x,     (size_t)dsm, (k0 - 128) + quad * 8, f32);
    else               a = load_a8(eattr, (size_t)pe,  (k0 - 256) + quad * 8, f32);
    const unsigned short* wp = P1 + ((size_t)(ks * 8) * 64 + lane) * 8;
#pragma unroll
    for (int ct = 0; ct < 8; ct++) {
      short8 b = *(const short8*)(wp + ct * 512);
      acc[ct] = __builtin_amdgcn_mfma_f32_16x16x32_bf16(a, b, acc[ct], 0, 0, 0);
    }
  }

  // bias + ReLU -> hs (wave-private rows; no barrier needed before own reads)
#pragma unroll
  for (int ct = 0; ct < 8; ct++) {
    const int col = ct * 16 + l15;
    const float bv = loads(b1, col, f32);
#pragma unroll
    for (int r = 0; r < 4; r++) {
      float v = acc[ct][r] + bv;
      hs[wid * 16 + quad * 4 + r][col] = f2bf(fmaxf(v, 0.f));
    }
  }

  // GEMM2: [64 x 128] @ [128 x 128]
  f32x4 acc2[8];
#pragma unroll
  for (int ct = 0; ct < 8; ct++) acc2[ct] = zero;
#pragma unroll
  for (int ks = 0; ks < 4; ks++) {
    short8 a = *(const short8*)&hs[wid * 16 + l15][ks * 32 + quad * 8];
    const unsigned short* wp = P2 + ((size_t)(ks * 8) * 64 + lane) * 8;
#pragma unroll
    for (int ct = 0; ct < 8; ct++) {
      short8 b = *(const short8*)(wp + ct * 512);
      acc2[ct] = __builtin_amdgcn_mfma_f32_16x16x32_bf16(a, b, acc2[ct], 0, 0, 0);
    }
  }

  float b2v[8];
#pragma unroll
  for (int ct = 0; ct < 8; ct++) b2v[ct] = loads(b2, ct * 16 + l15, f32);

  __syncthreads();  // all waves done reading hs before ms overwrites the union
#pragma unroll
  for (int ct = 0; ct < 8; ct++) {
    const int col = ct * 16 + l15;
#pragma unroll
    for (int r = 0; r < 4; r++) {
      const int e = base + wid * 16 + quad * 4 + r;
      ms[wid * 16 + quad * 4 + r][col] = (e < E) ? (acc2[ct][r] + b2v[ct]) : 0.0f;
    }
  }
  __syncthreads();

  // Segmented reduction over sorted dst runs. 2 threads/col (rows 0-31, 32-63);
  // run boundaries are wave-uniform (same dst sequence for all cols).
  const int col  = tid & 127;
  const int half = tid >> 7;
  const int r0 = half * 32;
  float sum = 0.0f;
  int cur = sdst_s[r0];
#pragma unroll 4
  for (int r = r0; r < r0 + 32; r++) {
    int d = sdst_s[r];
    if (d != cur) {
      atomicAdd(&aggf[(size_t)cur * HID + col], sum);
      sum = 0.0f; cur = d;
    }
    sum += ms[r][col];
  }
  atomicAdd(&aggf[(size_t)cur * HID + col], sum);
}

// ---------------------------------------------------------------------------
// Fallback edge kernel (round-2 structure): per-edge atomics / CAS.
// ---------------------------------------------------------------------------
__global__ __launch_bounds__(256) void edge_kernel_plain(
    const void* __restrict__ x, const int* __restrict__ eidx,
    const void* __restrict__ eattr,
    const unsigned short* __restrict__ P1, const void* __restrict__ b1,
    const unsigned short* __restrict__ P2, const void* __restrict__ b2,
    float* __restrict__ aggf, void* __restrict__ out,
    const int* __restrict__ flags, int E, int N, int small_mode) {
  __shared__ unsigned short hs[64][136];
  const bool f32 = flags[0] != 0;
  const bool i64 = flags[1] != 0;
  const int tid  = threadIdx.x;
  const int lane = tid & 63;
  const int wid  = tid >> 6;
  const int l15  = lane & 15;
  const int quad = lane >> 4;
  const int base = blockIdx.x * 64;

  int me = base + wid * 16 + l15;
  if (me >= E) me = E - 1;
  int src = get_src(eidx, i64, E, me);
  int dsm = get_dst(eidx, i64, E, me);
  src = min(max(src, 0), N - 1);
  dsm = min(max(dsm, 0), N - 1);

  f32x4 zero = {0.f, 0.f, 0.f, 0.f};
  f32x4 acc[8];
#pragma unroll
  for (int ct = 0; ct < 8; ct++) acc[ct] = zero;
#pragma unroll
  for (int ks = 0; ks < 12; ks++) {
    const int k0 = ks * 32;
    short8 a;
    if (k0 < 128)      a = load_a8(x,     (size_t)src, k0 + quad * 8, f32);
    else if (k0 < 256) a = load_a8(x,     (size_t)dsm, (k0 - 128) + quad * 8, f32);
    else               a = load_a8(eattr, (size_t)me,  (k0 - 256) + quad * 8, f32);
    const unsigned short* wp = P1 + ((size_t)(ks * 8) * 64 + lane) * 8;
#pragma unroll
    for (int ct = 0; ct < 8; ct++) {
      short8 b = *(const short8*)(wp + ct * 512);
      acc[ct] = __builtin_amdgcn_mfma_f32_16x16x32_bf16(a, b, acc[ct], 0, 0, 0);
    }
  }
#pragma unroll
  for (int ct = 0; ct < 8; ct++) {
    const int col = ct * 16 + l15;
    const float bv = loads(b1, col, f32);
#pragma unroll
    for (int r = 0; r < 4; r++)
      hs[wid * 16 + quad * 4 + r][col] = f2bf(fmaxf(acc[ct][r] + bv, 0.f));
  }
  __syncthreads();
  f32x4 acc2[8];
#pragma unroll
  for (int ct = 0; ct < 8; ct++) acc2[ct] = zero;
#pragma unroll
  for (int ks = 0; ks < 4; ks++) {
    short8 a = *(const short8*)&hs[wid * 16 + l15][ks * 32 + quad * 8];
    const unsigned short* wp = P2 + ((size_t)(ks * 8) * 64 + lane) * 8;
#pragma unroll
    for (int ct = 0; ct < 8; ct++) {
      short8 b = *(const short8*)(wp + ct * 512);
      acc2[ct] = __builtin_amdgcn_mfma_f32_16x16x32_bf16(a, b, acc2[ct], 0, 0, 0);
    }
  }
  float b2v[8];
#pragma unroll
  for (int ct = 0; ct < 8; ct++) b2v[ct] = loads(b2, ct * 16 + l15, f32);

  if (!small_mode || f32) {
    float* tgt = (!small_mode) ? aggf : (float*)out;
#pragma unroll
    for (int r = 0; r < 4; r++) {
      const int e = base + wid * 16 + quad * 4 + r;
      if (e < E) {
        int d = get_dst(eidx, i64, E, e);
        d = min(max(d, 0), N - 1);
        float* op = tgt + (size_t)d * HID + l15;
#pragma unroll
        for (int ct = 0; ct < 8; ct++) atomicAdd(op + ct * 16, acc2[ct][r] + b2v[ct]);
      }
    }
  } else {
#pragma unroll
    for (int ct = 0; ct < 8; ct++) {
      const int col = ct * 16 + l15;
#pragma unroll
      for (int r = 0; r < 4; r++)
        hs[wid * 16 + quad * 4 + r][col] = f2bf(acc2[ct][r] + b2v[ct]);
    }
    __syncthreads();
    const int row = tid >> 2;
    const int cg  = (tid & 3) * 32;
    const int e = base + row;
    if (e < E) {
      int d = get_dst(eidx, i64, E, e);
      d = min(max(d, 0), N - 1);
      unsigned int* orow = (unsigned int*)out + ((size_t)d * HID >> 1);
#pragma unroll
      for (int p = 0; p < 16; p++) {
        const int col = cg + p * 2;
        const float lo = bf2f(hs[row][col]);
        const float hi = bf2f(hs[row][col + 1]);
        unsigned int* wp = orow + (col >> 1);
        unsigned int old = *wp, assumed;
        do {
          assumed = old;
          unsigned int nv = (unsigned int)f2bf(bf2f((unsigned short)(assumed & 0xFFFF)) + lo)
                          | ((unsigned int)f2bf(bf2f((unsigned short)(assumed >> 16)) + hi) << 16);
          old = atomicCAS(wp, assumed, nv);
        } while (old != assumed);
      }
    }
  }
}

// ---------------------------------------------------------------------------
// Node kernel: u = relu([x|agg]@U1+ub1); upd = u@U2+ub2; out = LN(x+upd)*g+b
// ---------------------------------------------------------------------------
__global__ __launch_bounds__(256) void node_kernel(
    const void* __restrict__ x, const float* __restrict__ aggf,
    const unsigned short* __restrict__ PU1, const void* __restrict__ ub1,
    const unsigned short* __restrict__ PU2, const void* __restrict__ ub2,
    const void* __restrict__ gamma, const void* __restrict__ beta,
    void* __restrict__ out, const int* __restrict__ flags, int N, int small_mode) {
  __shared__ unsigned short hs[64][136];
  const bool f32 = flags[0] != 0;
  const int tid  = threadIdx.x;
  const int lane = tid & 63;
  const int wid  = tid >> 6;
  const int l15  = lane & 15;
  const int quad = lane >> 4;
  const int base = blockIdx.x * 64;

  int mn = base + wid * 16 + l15;
  if (mn >= N) mn = N - 1;

  const void* aggp = (!small_mode) ? (const void*)aggf : (const void*)out;
  const bool aggF32 = (!small_mode) ? true : f32;

  f32x4 zero = {0.f, 0.f, 0.f, 0.f};
  f32x4 acc[8];
#pragma unroll
  for (int ct = 0; ct < 8; ct++) acc[ct] = zero;
#pragma unroll
  for (int ks = 0; ks < 8; ks++) {
    const int k0 = ks * 32;
    short8 a;
    if (k0 < 128) a = load_a8(x,    (size_t)mn, k0 + quad * 8, f32);
    else          a = load_a8(aggp, (size_t)mn, (k0 - 128) + quad * 8, aggF32);
    const unsigned short* wp = PU1 + ((size_t)(ks * 8) * 64 + lane) * 8;
#pragma unroll
    for (int ct = 0; ct < 8; ct++) {
      short8 b = *(const short8*)(wp + ct * 512);
      acc[ct] = __builtin_amdgcn_mfma_f32_16x16x32_bf16(a, b, acc[ct], 0, 0, 0);
    }
  }
#pragma unroll
  for (int ct = 0; ct < 8; ct++) {
    const int col = ct * 16 + l15;
    const float bv = loads(ub1, col, f32);
#pragma unroll
    for (int r = 0; r < 4; r++)
      hs[wid * 16 + quad * 4 + r][col] = f2bf(fmaxf(acc[ct][r] + bv, 0.f));
  }
  __syncthreads();
  f32x4 acc2[8];
#pragma unroll
  for (int ct = 0; ct < 8; ct++) acc2[ct] = zero;
#pragma unroll
  for (int ks = 0; ks < 4; ks++) {
    short8 a = *(const short8*)&hs[wid * 16 + l15][ks * 32 + quad * 8];
    const unsigned short* wp = PU2 + ((size_t)(ks * 8) * 64 + lane) * 8;
#pragma unroll
    for (int ct = 0; ct < 8; ct++) {
      short8 b = *(const short8*)(wp + ct * 512);
      acc2[ct] = __builtin_amdgcn_mfma_f32_16x16x32_bf16(a, b, acc2[ct], 0, 0, 0);
    }
  }

  float vals[8][4];
  float s1[4] = {0.f, 0.f, 0.f, 0.f};
  float s2[4] = {0.f, 0.f, 0.f, 0.f};
#pragma unroll
  for (int ct = 0; ct < 8; ct++) {
    const int col = ct * 16 + l15;
    const float bv = loads(ub2, col, f32);
#pragma unroll
    for (int r = 0; r < 4; r++) {
      int row = base + wid * 16 + quad * 4 + r;
      int rc = row < N ? row : 0;
      float v = acc2[ct][r] + bv + loads(x, (size_t)rc * HID + col, f32);
      vals[ct][r] = v;
      s1[r] += v;
      s2[r] += v * v;
    }
  }
#pragma unroll
  for (int off = 1; off < 16; off <<= 1) {
#pragma unroll
    for (int r = 0; r < 4; r++) {
      s1[r] += __shfl_xor(s1[r], off, 16);
      s2[r] += __shfl_xor(s2[r], off, 16);
    }
  }
#pragma unroll
  for (int r = 0; r < 4; r++) {
    const int row = base + wid * 16 + quad * 4 + r;
    if (row < N) {
      const float mean = s1[r] * (1.0f / 128.0f);
      const float var  = fmaxf(s2[r] * (1.0f / 128.0f) - mean * mean, 0.0f);
      const float rstd = rsqrtf(var + 1e-5f);
#pragma unroll
      for (int ct = 0; ct < 8; ct++) {
        const int col = ct * 16 + l15;
        float o = (vals[ct][r] - mean) * rstd * loads(gamma, col, f32) + loads(beta, col, f32);
        if (f32) ((float*)out)[(size_t)row * HID + col] = o;
        else     ((unsigned short*)out)[(size_t)row * HID + col] = f2bf(o);
      }
    }
  }
}

// ---------------------------------------------------------------------------
extern "C" void kernel_launch(void* const* d_in, const int* in_sizes, int n_in,
                              void* d_out, int out_size, void* d_ws, size_t ws_size,
                              hipStream_t stream) {
  (void)n_in;
  const void* x     = d_in[0];
  const int*  eidx  = (const int*)d_in[1];
  const void* eattr = d_in[2];
  const void* W1  = d_in[3];
  const void* b1  = d_in[4];
  const void* W2  = d_in[5];
  const void* b2  = d_in[6];
  const void* U1  = d_in[7];
  const void* ub1 = d_in[8];
  const void* U2  = d_in[9];
  const void* ub2 = d_in[10];
  const void* gam = d_in[11];
  const void* bet = d_in[12];

  const int N = in_sizes[0] / HID;
  const int E = in_sizes[2] / HID;

  char* ws = (char*)d_ws;
  int* flags = (int*)ws;                                       // 256 B
  unsigned short* P1  = (unsigned short*)(ws + 256);
  unsigned short* P2  = (unsigned short*)(ws + 256 + 98304);
  unsigned short* PU1 = (unsigned short*)(ws + 256 + 131072);
  unsigned short* PU2 = (unsigned short*)(ws + 256 + 196608);
  const size_t agg_off = 256 + 229376;
  float* aggf = (float*)(ws + agg_off);
  const size_t agg_bytes = (size_t)N * HID * sizeof(float);

  size_t o = agg_off + agg_bytes;
  auto alignup = [](size_t v) { return (v + 255) & ~(size_t)255; };
  o = alignup(o);           size_t offs_off = o; o += (size_t)(N + 1) * 4;
  o = alignup(o);           size_t cur_off  = o; o += (size_t)(N + 1) * 4;
  o = alignup(o);           size_t ssrc_off = o; o += (size_t)E * 4;
  o = alignup(o);           size_t sdst_off = o; o += (size_t)E * 4;
  o = alignup(o);           size_t perm_off = o; o += (size_t)E * 4;
  const size_t need_sort  = o;
  const size_t need_basic = agg_off + agg_bytes;

  int* offsb = (int*)(ws + offs_off);
  int* curb  = (int*)(ws + cur_off);
  int* ssrc  = (int*)(ws + ssrc_off);
  int* sdst  = (int*)(ws + sdst_off);
  int* perm  = (int*)(ws + perm_off);

  const int mode = (ws_size >= need_sort) ? 2 : ((ws_size >= need_basic) ? 1 : 0);

  detect_kernel<<<1, 256, 0, stream>>>(x, eidx, flags);
  repack_all<<<448, 256, 0, stream>>>(W1, W2, U1, U2, P1, P2, PU1, PU2, flags);

  if (mode == 2) {
    hipMemsetAsync(aggf, 0, agg_bytes, stream);
    hipMemsetAsync(curb, 0, (size_t)(N + 1) * 4, stream);
    hist_kernel<<<(E + 255) / 256, 256, 0, stream>>>(eidx, curb, flags, E, N);
    scan_kernel<<<1, 1024, 0, stream>>>(curb, offsb, N);
    hipMemcpyAsync(curb, offsb, (size_t)(N + 1) * 4, hipMemcpyDeviceToDevice, stream);
    scatter_kernel<<<(E + 255) / 256, 256, 0, stream>>>(eidx, curb, ssrc, sdst, perm,
                                                        flags, E, N);
    edge_kernel_sorted<<<(E + 63) / 64, 256, 0, stream>>>(x, eattr, ssrc, sdst, perm,
                                                          P1, b1, P2, b2, aggf, flags, E, N);
    node_kernel<<<(N + 63) / 64, 256, 0, stream>>>(x, aggf, PU1, ub1, PU2, ub2,
                                                   gam, bet, d_out, flags, N, 0);
  } else if (mode == 1) {
    hipMemsetAsync(aggf, 0, agg_bytes, stream);
    edge_kernel_plain<<<(E + 63) / 64, 256, 0, stream>>>(x, eidx, eattr, P1, b1, P2, b2,
                                                         aggf, d_out, flags, E, N, 0);
    node_kernel<<<(N + 63) / 64, 256, 0, stream>>>(x, aggf, PU1, ub1, PU2, ub2,
                                                   gam, bet, d_out, flags, N, 0);
  } else {
    zero_out_kernel<<<1024, 256, 0, stream>>>((unsigned int*)d_out, flags, (long long)out_size);
    edge_kernel_plain<<<(E + 63) / 64, 256, 0, stream>>>(x, eidx, eattr, P1, b1, P2, b2,
                                                         aggf, d_out, flags, E, N, 1);
    node_kernel<<<(N + 63) / 64, 256, 0, stream>>>(x, aggf, PU1, ub1, PU2, ub2,
                                                   gam, bet, d_out, flags, N, 1);
  }
}

// Round 4
// 868.114 us; speedup vs baseline: 1.0402x; 1.0402x over previous
//
#include <hip/hip_runtime.h>

#define HID 128

typedef __attribute__((ext_vector_type(8))) short short8;
typedef __attribute__((ext_vector_type(4))) float f32x4;

__device__ __forceinline__ float bf2f(unsigned short u) {
  union { unsigned int u; float f; } c; c.u = ((unsigned int)u) << 16; return c.f;
}
__device__ __forceinline__ unsigned short f2bf(float f) {
  union { float f; unsigned int u; } c; c.f = f;
  unsigned int u = c.u;
  return (unsigned short)((u + 0x7FFFu + ((u >> 16) & 1u)) >> 16);  // RNE
}
__device__ __forceinline__ float loads(const void* p, size_t i, bool f32) {
  return f32 ? ((const float*)p)[i] : bf2f(((const unsigned short*)p)[i]);
}
__device__ __forceinline__ short8 load_a8(const void* base, size_t row, int k, bool f32) {
  if (!f32) return *(const short8*)((const unsigned short*)base + row * HID + k);
  const float* fp = (const float*)base + row * HID + k;
  f32x4 f0 = *(const f32x4*)fp;
  f32x4 f1 = *(const f32x4*)(fp + 4);
  short8 t;
  t[0] = (short)f2bf(f0[0]); t[1] = (short)f2bf(f0[1]);
  t[2] = (short)f2bf(f0[2]); t[3] = (short)f2bf(f0[3]);
  t[4] = (short)f2bf(f1[0]); t[5] = (short)f2bf(f1[1]);
  t[6] = (short)f2bf(f1[2]); t[7] = (short)f2bf(f1[3]);
  return t;
}

// ---------------------------------------------------------------------------
// Runtime dtype detection. flags[0]=1 -> fp32 floats; flags[1]=1 -> int64 idx.
// ---------------------------------------------------------------------------
__global__ void detect_kernel(const void* __restrict__ x,
                              const int* __restrict__ eidx,
                              int* __restrict__ flags) {
  __shared__ int bad, oddnz;
  if (threadIdx.x == 0) { bad = 0; oddnz = 0; }
  __syncthreads();
  const unsigned short* xu = (const unsigned short*)x;
  int mybad = 0;
  for (int i = threadIdx.x; i < 4096; i += 256) {
    int ef = (xu[i] >> 7) & 0xFF;
    if (!(ef == 0 || (ef >= 90 && ef <= 140))) mybad++;
  }
  if (mybad) atomicAdd(&bad, mybad);
  if (threadIdx.x < 128) {
    if (eidx[2 * threadIdx.x + 1] != 0) atomicAdd(&oddnz, 1);
  }
  __syncthreads();
  if (threadIdx.x == 0) {
    flags[0] = (bad > 409) ? 1 : 0;
    flags[1] = (oddnz == 0) ? 1 : 0;
  }
}

__device__ __forceinline__ int get_dst(const int* eidx, bool i64, int E, int e) {
  return i64 ? eidx[2 * (E + e)] : eidx[E + e];
}
__device__ __forceinline__ int get_src(const int* eidx, bool i64, int E, int e) {
  return i64 ? eidx[2 * e] : eidx[e];
}

__global__ void zero_out_kernel(unsigned int* __restrict__ out,
                                const int* __restrict__ flags, long long nelem) {
  bool f32 = flags[0] != 0;
  size_t words = (size_t)nelem * (f32 ? 2 : 1) / 2;
  for (size_t w = blockIdx.x * 256ull + threadIdx.x; w < words; w += (size_t)gridDim.x * 256ull)
    out[w] = 0u;
}

// ---------------------------------------------------------------------------
// Repack weights into MFMA B-fragment order (bf16).
// ---------------------------------------------------------------------------
__global__ void repack_all(const void* __restrict__ W1, const void* __restrict__ W2,
                           const void* __restrict__ U1, const void* __restrict__ U2,
                           unsigned short* __restrict__ P1, unsigned short* __restrict__ P2,
                           unsigned short* __restrict__ PU1, unsigned short* __restrict__ PU2,
                           const int* __restrict__ flags) {
  const bool f32 = flags[0] != 0;
  int idx = blockIdx.x * 256 + threadIdx.x;
  const int s1 = 384 * 128, s2 = s1 + 128 * 128, s3 = s2 + 256 * 128, s4 = s3 + 128 * 128;
  if (idx >= s4) return;
  const void* W; unsigned short* P; int off;
  if (idx < s1)      { W = W1; P = P1;  off = idx; }
  else if (idx < s2) { W = W2; P = P2;  off = idx - s1; }
  else if (idx < s3) { W = U1; P = PU1; off = idx - s2; }
  else               { W = U2; P = PU2; off = idx - s3; }
  int j = off & 7, lane = (off >> 3) & 63, ct = (off >> 9) & 7, ks = off >> 12;
  int k = ks * 32 + ((lane >> 4) << 3) + j;
  int n = ct * 16 + (lane & 15);
  P[off] = f2bf(loads(W, (size_t)k * 128 + n, f32));
}

// ---------------------------------------------------------------------------
// Sort machinery: histogram, multi-block 3-phase scan, rank scatter.
// ---------------------------------------------------------------------------
__global__ void hist_kernel(const int* __restrict__ eidx, int* __restrict__ counts,
                            const int* __restrict__ flags, int E, int N) {
  const bool i64 = flags[1] != 0;
  int e = blockIdx.x * 256 + threadIdx.x;
  if (e < E) {
    int d = get_dst(eidx, i64, E, e);
    d = min(max(d, 0), N - 1);
    atomicAdd(&counts[d], 1);
  }
}

// Phase A: per-1024-block exclusive scan -> curb; block totals -> bsum.
__global__ __launch_bounds__(1024) void scanA_kernel(const int* __restrict__ cnt,
                                                     int* __restrict__ curb,
                                                     int* __restrict__ bsum, int N) {
  __shared__ int wsum[16], wsum2[16];
  const int tid = threadIdx.x, lane = tid & 63, wid = tid >> 6;
  int i = blockIdx.x * 1024 + tid;
  int v = (i < N) ? cnt[i] : 0;
  int s = v;
#pragma unroll
  for (int off = 1; off < 64; off <<= 1) {
    int t = __shfl_up(s, off, 64);
    if (lane >= off) s += t;
  }
  if (lane == 63) wsum[wid] = s;
  __syncthreads();
  if (wid == 0 && lane < 16) {
    int w = wsum[lane];
#pragma unroll
    for (int off = 1; off < 16; off <<= 1) {
      int t = __shfl_up(w, off, 16);
      if (lane >= off) w += t;
    }
    wsum2[lane] = w;
    if (lane == 15) bsum[blockIdx.x] = w;
  }
  __syncthreads();
  int pre = (wid > 0) ? wsum2[wid - 1] : 0;
  if (i < N) curb[i] = pre + s - v;
}

// Phase B: serial exclusive scan of block sums (nb small).
__global__ void scanB_kernel(int* __restrict__ bsum, int nb) {
  if (threadIdx.x == 0 && blockIdx.x == 0) {
    int run = 0;
    for (int b = 0; b < nb; b++) { int t = bsum[b]; bsum[b] = run; run += t; }
  }
}

// Phase C: add block offsets.
__global__ __launch_bounds__(1024) void scanC_kernel(int* __restrict__ curb,
                                                     const int* __restrict__ bsum, int N) {
  int i = blockIdx.x * 1024 + threadIdx.x;
  if (i < N) curb[i] += bsum[blockIdx.x];
}

// rank[e] = sorted position; sdst[pos] = dst.
__global__ void scatter_rank_kernel(const int* __restrict__ eidx, int* __restrict__ cur,
                                    int* __restrict__ rank, int* __restrict__ sdst,
                                    const int* __restrict__ flags, int E, int N) {
  const bool i64 = flags[1] != 0;
  int e = blockIdx.x * 256 + threadIdx.x;
  if (e < E) {
    int d = get_dst(eidx, i64, E, e);
    d = min(max(d, 0), N - 1);
    int pos = atomicAdd(&cur[d], 1);
    rank[e] = pos;
    sdst[pos] = d;
  }
}

// ---------------------------------------------------------------------------
// x1_kernel: X1[n] = [ x[n]@W1a + b1 | x[n]@W1b ]  (bf16, N x 256)
// ---------------------------------------------------------------------------
__global__ __launch_bounds__(256) void x1_kernel(
    const void* __restrict__ x, const unsigned short* __restrict__ P1,
    const void* __restrict__ b1, unsigned short* __restrict__ X1,
    const int* __restrict__ flags, int N) {
  __shared__ unsigned short hs[64][264];
  const bool f32 = flags[0] != 0;
  const int tid = threadIdx.x, lane = tid & 63, wid = tid >> 6;
  const int l15 = lane & 15, quad = lane >> 4;
  const int base = blockIdx.x * 64;
  int mn = min(base + wid * 16 + l15, N - 1);

  f32x4 zero = {0.f, 0.f, 0.f, 0.f};
  f32x4 acca[8], accb[8];
#pragma unroll
  for (int ct = 0; ct < 8; ct++) { acca[ct] = zero; accb[ct] = zero; }
#pragma unroll
  for (int ks = 0; ks < 4; ks++) {
    short8 a = load_a8(x, (size_t)mn, ks * 32 + quad * 8, f32);
    const unsigned short* wpa = P1 + ((size_t)(ks * 8) * 64 + lane) * 8;
    const unsigned short* wpb = P1 + ((size_t)((ks + 4) * 8) * 64 + lane) * 8;
#pragma unroll
    for (int ct = 0; ct < 8; ct++) {
      short8 ba = *(const short8*)(wpa + ct * 512);
      short8 bb = *(const short8*)(wpb + ct * 512);
      acca[ct] = __builtin_amdgcn_mfma_f32_16x16x32_bf16(a, ba, acca[ct], 0, 0, 0);
      accb[ct] = __builtin_amdgcn_mfma_f32_16x16x32_bf16(a, bb, accb[ct], 0, 0, 0);
    }
  }
#pragma unroll
  for (int ct = 0; ct < 8; ct++) {
    const int col = ct * 16 + l15;
    const float bv = loads(b1, col, f32);
#pragma unroll
    for (int r = 0; r < 4; r++) {
      hs[wid * 16 + quad * 4 + r][col]       = f2bf(acca[ct][r] + bv);
      hs[wid * 16 + quad * 4 + r][128 + col] = f2bf(accb[ct][r]);
    }
  }
  __syncthreads();
  const int row = tid >> 2, part = tid & 3;
  if (base + row < N) {
    unsigned short* op = X1 + (size_t)(base + row) * 256 + part * 64;
#pragma unroll
    for (int j = 0; j < 8; j++)
      *(short8*)(op + j * 8) = *(const short8*)&hs[row][part * 64 + j * 8];
  }
}

// ---------------------------------------------------------------------------
// edgeB: per 64 unsorted edges: eattr@W1c -> +X1a[src]+X1b[dst] relu -> @W2
// -> bf16 msg scattered to sorted position msgbuf[rank[e]].
// ---------------------------------------------------------------------------
__global__ __launch_bounds__(256) void edgeB_kernel(
    const void* __restrict__ eattr, const int* __restrict__ eidx,
    const int* __restrict__ rank, const unsigned short* __restrict__ X1,
    const unsigned short* __restrict__ P1, const unsigned short* __restrict__ P2,
    unsigned short* __restrict__ msgbuf, const int* __restrict__ flags, int E, int N) {
  __shared__ unsigned short hsb[64][136];
  __shared__ int src_s[64], dst_s[64], rank_s[64];
  const bool f32 = flags[0] != 0;
  const bool i64 = flags[1] != 0;
  const int tid = threadIdx.x, lane = tid & 63, wid = tid >> 6;
  const int l15 = lane & 15, quad = lane >> 4;
  const int base = blockIdx.x * 64;

  if (tid < 64) {
    int e = min(base + tid, E - 1);
    int s = get_src(eidx, i64, E, e);
    int d = get_dst(eidx, i64, E, e);
    src_s[tid] = min(max(s, 0), N - 1);
    dst_s[tid] = min(max(d, 0), N - 1);
    rank_s[tid] = rank[e];
  }

  int me = min(base + wid * 16 + l15, E - 1);
  f32x4 zero = {0.f, 0.f, 0.f, 0.f};
  f32x4 acc[8];
#pragma unroll
  for (int ct = 0; ct < 8; ct++) acc[ct] = zero;
  // eattr @ W1c  (W1 rows 256..383 = P1 ks 8..11); eattr rows consecutive.
#pragma unroll
  for (int ks = 0; ks < 4; ks++) {
    short8 a = load_a8(eattr, (size_t)me, ks * 32 + quad * 8, f32);
    const unsigned short* wp = P1 + ((size_t)((ks + 8) * 8) * 64 + lane) * 8;
#pragma unroll
    for (int ct = 0; ct < 8; ct++) {
      short8 b = *(const short8*)(wp + ct * 512);
      acc[ct] = __builtin_amdgcn_mfma_f32_16x16x32_bf16(a, b, acc[ct], 0, 0, 0);
    }
  }
#pragma unroll
  for (int ct = 0; ct < 8; ct++) {
    const int col = ct * 16 + l15;
#pragma unroll
    for (int r = 0; r < 4; r++)
      hsb[wid * 16 + quad * 4 + r][col] = f2bf(acc[ct][r]);
  }
  __syncthreads();

  // Add gathered X1a[src] + X1b[dst], ReLU (row-major, coalesced 256 B rows).
#pragma unroll
  for (int it = 0; it < 4; it++) {
    const int r = it * 16 + (tid >> 4);
    const int cg = (tid & 15) * 8;
    short8 h8 = *(const short8*)&hsb[r][cg];
    short8 a8 = *(const short8*)(X1 + (size_t)src_s[r] * 256 + cg);
    short8 b8 = *(const short8*)(X1 + (size_t)dst_s[r] * 256 + 128 + cg);
    short8 o;
#pragma unroll
    for (int j = 0; j < 8; j++) {
      float v = bf2f((unsigned short)h8[j]) + bf2f((unsigned short)a8[j])
              + bf2f((unsigned short)b8[j]);
      o[j] = (short)f2bf(fmaxf(v, 0.f));
    }
    *(short8*)&hsb[r][cg] = o;
  }
  __syncthreads();

  // GEMM2: h @ W2 (wave-private rows).
  f32x4 acc2[8];
#pragma unroll
  for (int ct = 0; ct < 8; ct++) acc2[ct] = zero;
#pragma unroll
  for (int ks = 0; ks < 4; ks++) {
    short8 a = *(const short8*)&hsb[wid * 16 + l15][ks * 32 + quad * 8];
    const unsigned short* wp = P2 + ((size_t)(ks * 8) * 64 + lane) * 8;
#pragma unroll
    for (int ct = 0; ct < 8; ct++) {
      short8 b = *(const short8*)(wp + ct * 512);
      acc2[ct] = __builtin_amdgcn_mfma_f32_16x16x32_bf16(a, b, acc2[ct], 0, 0, 0);
    }
  }
#pragma unroll
  for (int ct = 0; ct < 8; ct++) {
    const int col = ct * 16 + l15;
#pragma unroll
    for (int r = 0; r < 4; r++)
      hsb[wid * 16 + quad * 4 + r][col] = f2bf(acc2[ct][r]);  // b2 folded in reduce
  }
  __syncthreads();

  const int row = tid >> 2, part = tid & 3;
  if (base + row < E) {
    unsigned short* mp = msgbuf + (size_t)rank_s[row] * HID + part * 32;
#pragma unroll
    for (int j = 0; j < 4; j++)
      *(short8*)(mp + j * 8) = *(const short8*)&hsb[row][part * 32 + j * 8];
  }
}

// ---------------------------------------------------------------------------
// reduceC: segmented sum of sorted bf16 messages (+cnt*b2) -> aggf atomics.
// Block = 256 edges; 64 col-pairs x 4 row-groups of 64.
// ---------------------------------------------------------------------------
__global__ __launch_bounds__(256) void reduce_kernel(
    const unsigned short* __restrict__ msgbuf, const int* __restrict__ sdst,
    const void* __restrict__ b2, float* __restrict__ aggf,
    const int* __restrict__ flags, int E) {
  __shared__ int sd[256];
  const bool f32 = flags[0] != 0;
  const int tid = threadIdx.x;
  const int base = blockIdx.x * 256;
  { int e = base + tid; sd[tid] = (e < E) ? sdst[e] : -1; }
  __syncthreads();
  const int pair = tid & 63;
  const int grp = tid >> 6;
  const int c0 = pair * 2;
  const float b2a = loads(b2, c0, f32);
  const float b2b = loads(b2, c0 + 1, f32);
  float sa = 0.f, sb = 0.f; int cnt = 0, cur = -1;
  for (int r = 0; r < 64; r++) {
    const int lr = grp * 64 + r;
    const int d = sd[lr];
    if (d < 0) break;
    if (d != cur) {
      if (cnt > 0) {
        atomicAdd(&aggf[(size_t)cur * HID + c0],     sa + cnt * b2a);
        atomicAdd(&aggf[(size_t)cur * HID + c0 + 1], sb + cnt * b2b);
      }
      sa = sb = 0.f; cnt = 0; cur = d;
    }
    unsigned int u = *(const unsigned int*)(msgbuf + (size_t)(base + lr) * HID + c0);
    sa += bf2f((unsigned short)(u & 0xFFFF));
    sb += bf2f((unsigned short)(u >> 16));
    cnt++;
  }
  if (cnt > 0) {
    atomicAdd(&aggf[(size_t)cur * HID + c0],     sa + cnt * b2a);
    atomicAdd(&aggf[(size_t)cur * HID + c0 + 1], sb + cnt * b2b);
  }
}

// ---------------------------------------------------------------------------
// Mode-2 fallback kernels (round-3 structure, kept intact).
// ---------------------------------------------------------------------------
__global__ __launch_bounds__(1024) void scan_kernel(const int* __restrict__ counts,
                                                    int* __restrict__ offs, int N) {
  __shared__ int wsum[16];
  __shared__ int wpre[16];
  __shared__ int carry_s;
  const int tid = threadIdx.x, lane = tid & 63, wid = tid >> 6;
  if (tid == 0) carry_s = 0;
  __syncthreads();
  for (int base = 0; base < N; base += 1024) {
    int i = base + tid;
    int v = (i < N) ? counts[i] : 0;
    int s = v;
#pragma unroll
    for (int off = 1; off < 64; off <<= 1) {
      int t = __shfl_up(s, off, 64);
      if (lane >= off) s += t;
    }
    if (lane == 63) wsum[wid] = s;
    __syncthreads();
    if (tid == 0) {
      int run = carry_s;
#pragma unroll
      for (int w = 0; w < 16; w++) { int t = wsum[w]; wpre[w] = run; run += t; }
      carry_s = run;
    }
    __syncthreads();
    if (i < N) offs[i] = wpre[wid] + s - v;
    __syncthreads();
  }
  if (tid == 0) offs[N] = carry_s;
}

__global__ void scatter_kernel(const int* __restrict__ eidx, int* __restrict__ cur,
                               int* __restrict__ ssrc, int* __restrict__ sdst,
                               int* __restrict__ perm,
                               const int* __restrict__ flags, int E, int N) {
  const bool i64 = flags[1] != 0;
  int e = blockIdx.x * 256 + threadIdx.x;
  if (e < E) {
    int d = get_dst(eidx, i64, E, e);
    int s = get_src(eidx, i64, E, e);
    d = min(max(d, 0), N - 1);
    s = min(max(s, 0), N - 1);
    int pos = atomicAdd(&cur[d], 1);
    ssrc[pos] = s;
    sdst[pos] = d;
    perm[pos] = e;
  }
}

__global__ __launch_bounds__(256) void edge_kernel_sorted(
    const void* __restrict__ x, const void* __restrict__ eattr,
    const int* __restrict__ ssrc, const int* __restrict__ sdst,
    const int* __restrict__ perm,
    const unsigned short* __restrict__ P1, const void* __restrict__ b1,
    const unsigned short* __restrict__ P2, const void* __restrict__ b2,
    float* __restrict__ aggf, const int* __restrict__ flags, int E, int N) {
  __shared__ __align__(16) char smem[64 * 132 * 4];
  __shared__ int sdst_s[64];
  unsigned short (*hs)[136] = (unsigned short (*)[136])smem;
  float (*ms)[132] = (float (*)[132])smem;
  const bool f32 = flags[0] != 0;
  const int tid = threadIdx.x, lane = tid & 63, wid = tid >> 6;
  const int l15 = lane & 15, quad = lane >> 4;
  const int base = blockIdx.x * 64;

  if (tid < 64) sdst_s[tid] = sdst[min(base + tid, E - 1)];

  int me = base + wid * 16 + l15;
  if (me >= E) me = E - 1;
  const int src = ssrc[me];
  const int dsm = sdst[me];
  const int pe  = perm[me];

  f32x4 zero = {0.f, 0.f, 0.f, 0.f};
  f32x4 acc[8];
#pragma unroll
  for (int ct = 0; ct < 8; ct++) acc[ct] = zero;
#pragma unroll
  for (int ks = 0; ks < 12; ks++) {
    const int k0 = ks * 32;
    short8 a;
    if (k0 < 128)      a = load_a8(x,     (size_t)src, k0 + quad * 8, f32);
    else if (k0 < 256) a = load_a8(x,     (size_t)dsm, (k0 - 128) + quad * 8, f32);
    else               a = load_a8(eattr, (size_t)pe,  (k0 - 256) + quad * 8, f32);
    const unsigned short* wp = P1 + ((size_t)(ks * 8) * 64 + lane) * 8;
#pragma unroll
    for (int ct = 0; ct < 8; ct++) {
      short8 b = *(const short8*)(wp + ct * 512);
      acc[ct] = __builtin_amdgcn_mfma_f32_16x16x32_bf16(a, b, acc[ct], 0, 0, 0);
    }
  }
#pragma unroll
  for (int ct = 0; ct < 8; ct++) {
    const int col = ct * 16 + l15;
    const float bv = loads(b1, col, f32);
#pragma unroll
    for (int r = 0; r < 4; r++)
      hs[wid * 16 + quad * 4 + r][col] = f2bf(fmaxf(acc[ct][r] + bv, 0.f));
  }
  f32x4 acc2[8];
#pragma unroll
  for (int ct = 0; ct < 8; ct++) acc2[ct] = zero;
#pragma unroll
  for (int ks = 0; ks < 4; ks++) {
    short8 a = *(const short8*)&hs[wid * 16 + l15][ks * 32 + quad * 8];
    const unsigned short* wp = P2 + ((size_t)(ks * 8) * 64 + lane) * 8;
#pragma unroll
    for (int ct = 0; ct < 8; ct++) {
      short8 b = *(const short8*)(wp + ct * 512);
      acc2[ct] = __builtin_amdgcn_mfma_f32_16x16x32_bf16(a, b, acc2[ct], 0, 0, 0);
    }
  }
  float b2v[8];
#pragma unroll
  for (int ct = 0; ct < 8; ct++) b2v[ct] = loads(b2, ct * 16 + l15, f32);
  __syncthreads();
#pragma unroll
  for (int ct = 0; ct < 8; ct++) {
    const int col = ct * 16 + l15;
#pragma unroll
    for (int r = 0; r < 4; r++) {
      const int e = base + wid * 16 + quad * 4 + r;
      ms[wid * 16 + quad * 4 + r][col] = (e < E) ? (acc2[ct][r] + b2v[ct]) : 0.0f;
    }
  }
  __syncthreads();
  const int col  = tid & 127;
  const int half = tid >> 7;
  const int r0 = half * 32;
  float sum = 0.0f;
  int cur = sdst_s[r0];
#pragma unroll 4
  for (int r = r0; r < r0 + 32; r++) {
    int d = sdst_s[r];
    if (d != cur) {
      atomicAdd(&aggf[(size_t)cur * HID + col], sum);
      sum = 0.0f; cur = d;
    }
    sum += ms[r][col];
  }
  atomicAdd(&aggf[(size_t)cur * HID + col], sum);
}

__global__ __launch_bounds__(256) void edge_kernel_plain(
    const void* __restrict__ x, const int* __restrict__ eidx,
    const void* __restrict__ eattr,
    const unsigned short* __restrict__ P1, const void* __restrict__ b1,
    const unsigned short* __restrict__ P2, const void* __restrict__ b2,
    float* __restrict__ aggf, void* __restrict__ out,
    const int* __restrict__ flags, int E, int N, int small_mode) {
  __shared__ unsigned short hs[64][136];
  const bool f32 = flags[0] != 0;
  const bool i64 = flags[1] != 0;
  const int tid = threadIdx.x, lane = tid & 63, wid = tid >> 6;
  const int l15 = lane & 15, quad = lane >> 4;
  const int base = blockIdx.x * 64;

  int me = base + wid * 16 + l15;
  if (me >= E) me = E - 1;
  int src = get_src(eidx, i64, E, me);
  int dsm = get_dst(eidx, i64, E, me);
  src = min(max(src, 0), N - 1);
  dsm = min(max(dsm, 0), N - 1);

  f32x4 zero = {0.f, 0.f, 0.f, 0.f};
  f32x4 acc[8];
#pragma unroll
  for (int ct = 0; ct < 8; ct++) acc[ct] = zero;
#pragma unroll
  for (int ks = 0; ks < 12; ks++) {
    const int k0 = ks * 32;
    short8 a;
    if (k0 < 128)      a = load_a8(x,     (size_t)src, k0 + quad * 8, f32);
    else if (k0 < 256) a = load_a8(x,     (size_t)dsm, (k0 - 128) + quad * 8, f32);
    else               a = load_a8(eattr, (size_t)me,  (k0 - 256) + quad * 8, f32);
    const unsigned short* wp = P1 + ((size_t)(ks * 8) * 64 + lane) * 8;
#pragma unroll
    for (int ct = 0; ct < 8; ct++) {
      short8 b = *(const short8*)(wp + ct * 512);
      acc[ct] = __builtin_amdgcn_mfma_f32_16x16x32_bf16(a, b, acc[ct], 0, 0, 0);
    }
  }
#pragma unroll
  for (int ct = 0; ct < 8; ct++) {
    const int col = ct * 16 + l15;
    const float bv = loads(b1, col, f32);
#pragma unroll
    for (int r = 0; r < 4; r++)
      hs[wid * 16 + quad * 4 + r][col] = f2bf(fmaxf(acc[ct][r] + bv, 0.f));
  }
  __syncthreads();
  f32x4 acc2[8];
#pragma unroll
  for (int ct = 0; ct < 8; ct++) acc2[ct] = zero;
#pragma unroll
  for (int ks = 0; ks < 4; ks++) {
    short8 a = *(const short8*)&hs[wid * 16 + l15][ks * 32 + quad * 8];
    const unsigned short* wp = P2 + ((size_t)(ks * 8) * 64 + lane) * 8;
#pragma unroll
    for (int ct = 0; ct < 8; ct++) {
      short8 b = *(const short8*)(wp + ct * 512);
      acc2[ct] = __builtin_amdgcn_mfma_f32_16x16x32_bf16(a, b, acc2[ct], 0, 0, 0);
    }
  }
  float b2v[8];
#pragma unroll
  for (int ct = 0; ct < 8; ct++) b2v[ct] = loads(b2, ct * 16 + l15, f32);

  if (!small_mode || f32) {
    float* tgt = (!small_mode) ? aggf : (float*)out;
#pragma unroll
    for (int r = 0; r < 4; r++) {
      const int e = base + wid * 16 + quad * 4 + r;
      if (e < E) {
        int d = get_dst(eidx, i64, E, e);
        d = min(max(d, 0), N - 1);
        float* op = tgt + (size_t)d * HID + l15;
#pragma unroll
        for (int ct = 0; ct < 8; ct++) atomicAdd(op + ct * 16, acc2[ct][r] + b2v[ct]);
      }
    }
  } else {
#pragma unroll
    for (int ct = 0; ct < 8; ct++) {
      const int col = ct * 16 + l15;
#pragma unroll
      for (int r = 0; r < 4; r++)
        hs[wid * 16 + quad * 4 + r][col] = f2bf(acc2[ct][r] + b2v[ct]);
    }
    __syncthreads();
    const int row = tid >> 2;
    const int cg  = (tid & 3) * 32;
    const int e = base + row;
    if (e < E) {
      int d = get_dst(eidx, i64, E, e);
      d = min(max(d, 0), N - 1);
      unsigned int* orow = (unsigned int*)out + ((size_t)d * HID >> 1);
#pragma unroll
      for (int p = 0; p < 16; p++) {
        const int col = cg + p * 2;
        const float lo = bf2f(hs[row][col]);
        const float hi = bf2f(hs[row][col + 1]);
        unsigned int* wp = orow + (col >> 1);
        unsigned int old = *wp, assumed;
        do {
          assumed = old;
          unsigned int nv = (unsigned int)f2bf(bf2f((unsigned short)(assumed & 0xFFFF)) + lo)
                          | ((unsigned int)f2bf(bf2f((unsigned short)(assumed >> 16)) + hi) << 16);
          old = atomicCAS(wp, assumed, nv);
        } while (old != assumed);
      }
    }
  }
}

// ---------------------------------------------------------------------------
// Node kernel: u = relu([x|agg]@U1+ub1); upd = u@U2+ub2; out = LN(x+upd)*g+b
// ---------------------------------------------------------------------------
__global__ __launch_bounds__(256) void node_kernel(
    const void* __restrict__ x, const float* __restrict__ aggf,
    const unsigned short* __restrict__ PU1, const void* __restrict__ ub1,
    const unsigned short* __restrict__ PU2, const void* __restrict__ ub2,
    const void* __restrict__ gamma, const void* __restrict__ beta,
    void* __restrict__ out, const int* __restrict__ flags, int N, int small_mode) {
  __shared__ unsigned short hs[64][136];
  const bool f32 = flags[0] != 0;
  const int tid = threadIdx.x, lane = tid & 63, wid = tid >> 6;
  const int l15 = lane & 15, quad = lane >> 4;
  const int base = blockIdx.x * 64;

  int mn = base + wid * 16 + l15;
  if (mn >= N) mn = N - 1;

  const void* aggp = (!small_mode) ? (const void*)aggf : (const void*)out;
  const bool aggF32 = (!small_mode) ? true : f32;

  f32x4 zero = {0.f, 0.f, 0.f, 0.f};
  f32x4 acc[8];
#pragma unroll
  for (int ct = 0; ct < 8; ct++) acc[ct] = zero;
#pragma unroll
  for (int ks = 0; ks < 8; ks++) {
    const int k0 = ks * 32;
    short8 a;
    if (k0 < 128) a = load_a8(x,    (size_t)mn, k0 + quad * 8, f32);
    else          a = load_a8(aggp, (size_t)mn, (k0 - 128) + quad * 8, aggF32);
    const unsigned short* wp = PU1 + ((size_t)(ks * 8) * 64 + lane) * 8;
#pragma unroll
    for (int ct = 0; ct < 8; ct++) {
      short8 b = *(const short8*)(wp + ct * 512);
      acc[ct] = __builtin_amdgcn_mfma_f32_16x16x32_bf16(a, b, acc[ct], 0, 0, 0);
    }
  }
#pragma unroll
  for (int ct = 0; ct < 8; ct++) {
    const int col = ct * 16 + l15;
    const float bv = loads(ub1, col, f32);
#pragma unroll
    for (int r = 0; r < 4; r++)
      hs[wid * 16 + quad * 4 + r][col] = f2bf(fmaxf(acc[ct][r] + bv, 0.f));
  }
  __syncthreads();
  f32x4 acc2[8];
#pragma unroll
  for (int ct = 0; ct < 8; ct++) acc2[ct] = zero;
#pragma unroll
  for (int ks = 0; ks < 4; ks++) {
    short8 a = *(const short8*)&hs[wid * 16 + l15][ks * 32 + quad * 8];
    const unsigned short* wp = PU2 + ((size_t)(ks * 8) * 64 + lane) * 8;
#pragma unroll
    for (int ct = 0; ct < 8; ct++) {
      short8 b = *(const short8*)(wp + ct * 512);
      acc2[ct] = __builtin_amdgcn_mfma_f32_16x16x32_bf16(a, b, acc2[ct], 0, 0, 0);
    }
  }

  float vals[8][4];
  float s1[4] = {0.f, 0.f, 0.f, 0.f};
  float s2[4] = {0.f, 0.f, 0.f, 0.f};
#pragma unroll
  for (int ct = 0; ct < 8; ct++) {
    const int col = ct * 16 + l15;
    const float bv = loads(ub2, col, f32);
#pragma unroll
    for (int r = 0; r < 4; r++) {
      int row = base + wid * 16 + quad * 4 + r;
      int rc = row < N ? row : 0;
      float v = acc2[ct][r] + bv + loads(x, (size_t)rc * HID + col, f32);
      vals[ct][r] = v;
      s1[r] += v;
      s2[r] += v * v;
    }
  }
#pragma unroll
  for (int off = 1; off < 16; off <<= 1) {
#pragma unroll
    for (int r = 0; r < 4; r++) {
      s1[r] += __shfl_xor(s1[r], off, 16);
      s2[r] += __shfl_xor(s2[r], off, 16);
    }
  }
#pragma unroll
  for (int r = 0; r < 4; r++) {
    const int row = base + wid * 16 + quad * 4 + r;
    if (row < N) {
      const float mean = s1[r] * (1.0f / 128.0f);
      const float var  = fmaxf(s2[r] * (1.0f / 128.0f) - mean * mean, 0.0f);
      const float rstd = rsqrtf(var + 1e-5f);
#pragma unroll
      for (int ct = 0; ct < 8; ct++) {
        const int col = ct * 16 + l15;
        float o = (vals[ct][r] - mean) * rstd * loads(gamma, col, f32) + loads(beta, col, f32);
        if (f32) ((float*)out)[(size_t)row * HID + col] = o;
        else     ((unsigned short*)out)[(size_t)row * HID + col] = f2bf(o);
      }
    }
  }
}

// ---------------------------------------------------------------------------
extern "C" void kernel_launch(void* const* d_in, const int* in_sizes, int n_in,
                              void* d_out, int out_size, void* d_ws, size_t ws_size,
                              hipStream_t stream) {
  (void)n_in;
  const void* x     = d_in[0];
  const int*  eidx  = (const int*)d_in[1];
  const void* eattr = d_in[2];
  const void* W1  = d_in[3];
  const void* b1  = d_in[4];
  const void* W2  = d_in[5];
  const void* b2  = d_in[6];
  const void* U1  = d_in[7];
  const void* ub1 = d_in[8];
  const void* U2  = d_in[9];
  const void* ub2 = d_in[10];
  const void* gam = d_in[11];
  const void* bet = d_in[12];

  const int N = in_sizes[0] / HID;
  const int E = in_sizes[2] / HID;

  char* ws = (char*)d_ws;
  auto alignup = [](size_t v) { return (v + 255) & ~(size_t)255; };

  int* flags = (int*)ws;                                       // 256 B
  unsigned short* P1  = (unsigned short*)(ws + 256);
  unsigned short* P2  = (unsigned short*)(ws + 256 + 98304);
  unsigned short* PU1 = (unsigned short*)(ws + 256 + 131072);
  unsigned short* PU2 = (unsigned short*)(ws + 256 + 196608);
  const size_t agg_off = 256 + 229376;
  float* aggf = (float*)(ws + agg_off);
  const size_t agg_bytes = (size_t)N * HID * sizeof(float);
  const size_t need_basic = agg_off + agg_bytes;

  // ---- mode-3 layout ----
  size_t o3 = alignup(need_basic);
  size_t cnt_off  = o3; o3 = alignup(o3 + (size_t)(N + 64) * 4);
  size_t cur_off  = o3; o3 = alignup(o3 + (size_t)(N + 64) * 4);
  size_t bsum_off = o3; o3 = alignup(o3 + 1024);
  size_t rank_off = o3; o3 = alignup(o3 + (size_t)E * 4);
  size_t sds3_off = o3; o3 = alignup(o3 + (size_t)E * 4);
  size_t x1_off   = o3; o3 = alignup(o3 + (size_t)N * 256 * 2);
  size_t msg_off  = o3; o3 = alignup(o3 + (size_t)E * HID * 2);
  const size_t need3 = o3;

  // ---- mode-2 layout (round-3) ----
  size_t o2 = alignup(need_basic);
  size_t offs_off = o2; o2 = alignup(o2 + (size_t)(N + 1) * 4);
  size_t cur2_off = o2; o2 = alignup(o2 + (size_t)(N + 1) * 4);
  size_t ssrc_off = o2; o2 = alignup(o2 + (size_t)E * 4);
  size_t sds2_off = o2; o2 = alignup(o2 + (size_t)E * 4);
  size_t perm_off = o2; o2 = alignup(o2 + (size_t)E * 4);
  const size_t need2 = o2;

  const int mode = (ws_size >= need3) ? 3
                 : (ws_size >= need2) ? 2
                 : (ws_size >= need_basic) ? 1 : 0;

  detect_kernel<<<1, 256, 0, stream>>>(x, eidx, flags);
  repack_all<<<448, 256, 0, stream>>>(W1, W2, U1, U2, P1, P2, PU1, PU2, flags);

  if (mode == 3) {
    int* cntb = (int*)(ws + cnt_off);
    int* curb = (int*)(ws + cur_off);
    int* bsum = (int*)(ws + bsum_off);
    int* rank = (int*)(ws + rank_off);
    int* sdst = (int*)(ws + sds3_off);
    unsigned short* X1     = (unsigned short*)(ws + x1_off);
    unsigned short* msgbuf = (unsigned short*)(ws + msg_off);
    const int nb = (N + 1023) / 1024;

    hipMemsetAsync(aggf, 0, agg_bytes, stream);
    hipMemsetAsync(cntb, 0, (size_t)N * 4, stream);
    hist_kernel<<<(E + 255) / 256, 256, 0, stream>>>(eidx, cntb, flags, E, N);
    scanA_kernel<<<nb, 1024, 0, stream>>>(cntb, curb, bsum, N);
    scanB_kernel<<<1, 64, 0, stream>>>(bsum, nb);
    scanC_kernel<<<nb, 1024, 0, stream>>>(curb, bsum, N);
    scatter_rank_kernel<<<(E + 255) / 256, 256, 0, stream>>>(eidx, curb, rank, sdst,
                                                             flags, E, N);
    x1_kernel<<<(N + 63) / 64, 256, 0, stream>>>(x, P1, b1, X1, flags, N);
    edgeB_kernel<<<(E + 63) / 64, 256, 0, stream>>>(eattr, eidx, rank, X1, P1, P2,
                                                    msgbuf, flags, E, N);
    reduce_kernel<<<(E + 255) / 256, 256, 0, stream>>>(msgbuf, sdst, b2, aggf, flags, E);
    node_kernel<<<(N + 63) / 64, 256, 0, stream>>>(x, aggf, PU1, ub1, PU2, ub2,
                                                   gam, bet, d_out, flags, N, 0);
  } else if (mode == 2) {
    int* offsb = (int*)(ws + offs_off);
    int* curb  = (int*)(ws + cur2_off);
    int* ssrc  = (int*)(ws + ssrc_off);
    int* sdst  = (int*)(ws + sds2_off);
    int* perm  = (int*)(ws + perm_off);
    hipMemsetAsync(aggf, 0, agg_bytes, stream);
    hipMemsetAsync(curb, 0, (size_t)(N + 1) * 4, stream);
    hist_kernel<<<(E + 255) / 256, 256, 0, stream>>>(eidx, curb, flags, E, N);
    scan_kernel<<<1, 1024, 0, stream>>>(curb, offsb, N);
    hipMemcpyAsync(curb, offsb, (size_t)(N + 1) * 4, hipMemcpyDeviceToDevice, stream);
    scatter_kernel<<<(E + 255) / 256, 256, 0, stream>>>(eidx, curb, ssrc, sdst, perm,
                                                        flags, E, N);
    edge_kernel_sorted<<<(E + 63) / 64, 256, 0, stream>>>(x, eattr, ssrc, sdst, perm,
                                                          P1, b1, P2, b2, aggf, flags, E, N);
    node_kernel<<<(N + 63) / 64, 256, 0, stream>>>(x, aggf, PU1, ub1, PU2, ub2,
                                                   gam, bet, d_out, flags, N, 0);
  } else if (mode == 1) {
    hipMemsetAsync(aggf, 0, agg_bytes, stream);
    edge_kernel_plain<<<(E + 63) / 64, 256, 0, stream>>>(x, eidx, eattr, P1, b1, P2, b2,
                                                         aggf, d_out, flags, E, N, 0);
    node_kernel<<<(N + 63) / 64, 256, 0, stream>>>(x, aggf, PU1, ub1, PU2, ub2,
                                                   gam, bet, d_out, flags, N, 0);
  } else {
    zero_out_kernel<<<1024, 256, 0, stream>>>((unsigned int*)d_out, flags, (long long)out_size);
    edge_kernel_plain<<<(E + 63) / 64, 256, 0, stream>>>(x, eidx, eattr, P1, b1, P2, b2,
                                                         aggf, d_out, flags, E, N, 1);
    node_kernel<<<(N + 63) / 64, 256, 0, stream>>>(x, aggf, PU1, ub1, PU2, ub2,
                                                   gam, bet, d_out, flags, N, 1);
  }
}